// Round 2
// baseline (8443.817 us; speedup 1.0000x reference)
//
#include <hip/hip_runtime.h>
#include <hip/hip_bf16.h>

#define N_NODES 100000
#define N_EDGES 800000
// IN=128, HID=256, OUT=128

// ---------------- count kernel ----------------
__global__ void count_k(const int* __restrict__ dst, float* __restrict__ cnt, int E) {
    int i = blockIdx.x * blockDim.x + threadIdx.x;
    if (i < E) atomicAdd(&cnt[dst[i]], 1.0f);
}

// ---------------- scatter kernel: 128-ch feature, float4 groups ----------------
// one thread per (edge, 4-channel group); 32 groups per edge
__global__ void scatter128_k(const int* __restrict__ src, const int* __restrict__ dst,
                             const float* __restrict__ feat, float* __restrict__ acc, int E) {
    long long idx = (long long)blockIdx.x * blockDim.x + threadIdx.x;
    long long total = (long long)E * 32;
    if (idx >= total) return;
    int e = (int)(idx >> 5);
    int g = (int)(idx & 31);
    int s = src[e], d = dst[e];
    float4 v = ((const float4*)feat)[(long long)s * 32 + g];
    float* p = acc + ((long long)d * 32 + g) * 4;
    atomicAdd(p + 0, v.x);
    atomicAdd(p + 1, v.y);
    atomicAdd(p + 2, v.z);
    atomicAdd(p + 3, v.w);
}

// ---------------- GEMM1: h = relu(mean1 @ W1l.T + b1l + x @ W1r.T) ----------------
// block = 256 threads, 16 nodes/block. thread t: node = t>>4, computes 16 outputs (oq=t&15)
__global__ __launch_bounds__(256) void gemm1_k(
        const float* __restrict__ x, const float* __restrict__ agg1, const float* __restrict__ cnt,
        const float* __restrict__ W1l, const float* __restrict__ b1l, const float* __restrict__ W1r,
        float* __restrict__ h, int N) {
    __shared__ float xs[16][132];   // +4 pad: float4-aligned rows, conflict-spread banks
    __shared__ float ms[16][132];
    int n0 = blockIdx.x * 16;
    int tid = threadIdx.x;

    // stage 16 x-rows and 16 mean-rows (512 float4 each)
    for (int i = tid; i < 16 * 32; i += 256) {
        int node = i >> 5, g = i & 31;
        int gn = n0 + node;
        float4 xv = make_float4(0, 0, 0, 0), av = make_float4(0, 0, 0, 0);
        float c = 1.0f;
        if (gn < N) {
            xv = ((const float4*)x)[(long long)gn * 32 + g];
            av = ((const float4*)agg1)[(long long)gn * 32 + g];
            c = fmaxf(cnt[gn], 1.0f);
        }
        float rc = 1.0f / c;
        av.x *= rc; av.y *= rc; av.z *= rc; av.w *= rc;
        ((float4*)&xs[node][0])[g] = xv;
        ((float4*)&ms[node][0])[g] = av;
    }
    __syncthreads();

    int node = tid >> 4;
    int oq = tid & 15;
    int gn = n0 + node;
    float acc[16];
#pragma unroll
    for (int j = 0; j < 16; j++) acc[j] = b1l[oq * 16 + j];

    for (int k4 = 0; k4 < 32; k4++) {
        float4 xv = ((const float4*)&xs[node][0])[k4];
        float4 mv = ((const float4*)&ms[node][0])[k4];
#pragma unroll
        for (int j = 0; j < 16; j++) {
            int o = oq * 16 + j;
            float4 wr = ((const float4*)W1r)[o * 32 + k4];
            float4 wl = ((const float4*)W1l)[o * 32 + k4];
            acc[j] += xv.x * wr.x + xv.y * wr.y + xv.z * wr.z + xv.w * wr.w
                    + mv.x * wl.x + mv.y * wl.y + mv.z * wl.z + mv.w * wl.w;
        }
    }
    if (gn < N) {
#pragma unroll
        for (int j = 0; j < 16; j++)
            h[(long long)gn * 256 + oq * 16 + j] = fmaxf(acc[j], 0.0f);
    }
}

// ---------------- GEMM2: g = h @ W2l.T ; r2 = h @ W2r.T ----------------
// block = 256 threads, 16 nodes/block. oq<8 -> g outputs, oq>=8 -> r2 outputs
__global__ __launch_bounds__(256) void gemm2_k(
        const float* __restrict__ h,
        const float* __restrict__ W2l, const float* __restrict__ W2r,
        float* __restrict__ g, float* __restrict__ r2, int N) {
    __shared__ float hs[16][260];   // 256 + 4 pad
    int n0 = blockIdx.x * 16;
    int tid = threadIdx.x;

    for (int i = tid; i < 16 * 64; i += 256) {
        int node = i >> 6, gq = i & 63;
        int gn = n0 + node;
        float4 v = make_float4(0, 0, 0, 0);
        if (gn < N) v = ((const float4*)h)[(long long)gn * 64 + gq];
        ((float4*)&hs[node][0])[gq] = v;
    }
    __syncthreads();

    int node = tid >> 4;
    int oq = tid & 15;
    int gn = n0 + node;
    const float* W = (oq < 8) ? W2l : W2r;
    int obase = (oq & 7) * 16;
    float acc[16];
#pragma unroll
    for (int j = 0; j < 16; j++) acc[j] = 0.0f;

    for (int k4 = 0; k4 < 64; k4++) {
        float4 hv = ((const float4*)&hs[node][0])[k4];
#pragma unroll
        for (int j = 0; j < 16; j++) {
            float4 w = ((const float4*)W)[(obase + j) * 64 + k4];
            acc[j] += hv.x * w.x + hv.y * w.y + hv.z * w.z + hv.w * w.w;
        }
    }
    if (gn < N) {
        float* dp = (oq < 8) ? g : r2;
#pragma unroll
        for (int j = 0; j < 16; j++)
            dp[(long long)gn * 128 + obase + j] = acc[j];
    }
}

// ---------------- final: out = out/max(cnt,1) + b2l + r2 ----------------
__global__ void final_k(float* __restrict__ out, const float* __restrict__ r2,
                        const float* __restrict__ cnt, const float* __restrict__ b2l, int N) {
    long long i = (long long)blockIdx.x * blockDim.x + threadIdx.x;
    if (i >= (long long)N * 32) return;
    int n = (int)(i >> 5);
    int g = (int)(i & 31);
    float c = fmaxf(cnt[n], 1.0f);
    float rc = 1.0f / c;
    float4 a = ((float4*)out)[i];
    float4 r = ((const float4*)r2)[i];
    float4 b = ((const float4*)b2l)[g];
    float4 o;
    o.x = a.x * rc + r.x + b.x;
    o.y = a.y * rc + r.y + b.y;
    o.z = a.z * rc + r.z + b.z;
    o.w = a.w * rc + r.w + b.w;
    ((float4*)out)[i] = o;
}

extern "C" void kernel_launch(void* const* d_in, const int* in_sizes, int n_in,
                              void* d_out, int out_size, void* d_ws, size_t ws_size,
                              hipStream_t stream) {
    const float* x   = (const float*)d_in[0];
    const int*   ei  = (const int*)d_in[1];     // [2, E]: src = ei[0..E), dst = ei[E..2E)
    const float* W1l = (const float*)d_in[2];
    const float* b1l = (const float*)d_in[3];
    const float* W1r = (const float*)d_in[4];
    const float* W2l = (const float*)d_in[5];
    const float* b2l = (const float*)d_in[6];
    const float* W2r = (const float*)d_in[7];
    float* out = (float*)d_out;

    const int N = N_NODES, E = N_EDGES;
    const int* srcI = ei;
    const int* dstI = ei + E;

    // workspace layout (bytes, 512-aligned)
    char* ws = (char*)d_ws;
    size_t off = 0;
    auto alloc = [&](size_t bytes) {
        size_t o = off;
        off += (bytes + 511) & ~(size_t)511;
        return o;
    };
    size_t off_cnt  = alloc((size_t)N * 4);            // [N]
    size_t off_agg1 = alloc((size_t)N * 128 * 4);      // [N,128] — reused as g after gemm1
    size_t off_h    = alloc((size_t)N * 256 * 4);      // [N,256]
    size_t off_r2   = alloc((size_t)N * 128 * 4);      // [N,128]
    float* cnt  = (float*)(ws + off_cnt);
    float* agg1 = (float*)(ws + off_agg1);
    float* g    = (float*)(ws + off_agg1);             // reuse agg1 region
    float* h    = (float*)(ws + off_h);
    float* r2   = (float*)(ws + off_r2);

    // zero accumulators (harness does not re-poison between replays)
    (void)hipMemsetAsync(cnt, 0, (size_t)N * 4, stream);
    (void)hipMemsetAsync(agg1, 0, (size_t)N * 128 * 4, stream);
    (void)hipMemsetAsync(out, 0, (size_t)N * 128 * 4, stream);

    // counts
    count_k<<<(E + 255) / 256, 256, 0, stream>>>(dstI, cnt, E);

    // layer 1: scatter x -> agg1
    {
        long long total = (long long)E * 32;
        int blocks = (int)((total + 255) / 256);
        scatter128_k<<<blocks, 256, 0, stream>>>(srcI, dstI, x, agg1, E);
    }

    // gemm1: h = relu(mean1@W1l.T + b1l + x@W1r.T)
    gemm1_k<<<(N + 15) / 16, 256, 0, stream>>>(x, agg1, cnt, W1l, b1l, W1r, h, N);

    // gemm2: g = h@W2l.T, r2 = h@W2r.T
    gemm2_k<<<(N + 15) / 16, 256, 0, stream>>>(h, W2l, W2r, g, r2, N);

    // layer 2: scatter g -> out (segment sum)
    {
        long long total = (long long)E * 32;
        int blocks = (int)((total + 255) / 256);
        scatter128_k<<<blocks, 256, 0, stream>>>(srcI, dstI, g, out, E);
    }

    // final: out = out/max(cnt,1) + b2l + r2
    {
        long long total = (long long)N * 32;
        int blocks = (int)((total + 255) / 256);
        final_k<<<blocks, 256, 0, stream>>>(out, r2, cnt, b2l, N);
    }
}

// Round 4
// 3242.929 us; speedup vs baseline: 2.6038x; 2.6038x over previous
//
#include <hip/hip_runtime.h>
#include <hip/hip_bf16.h>

#define N_NODES 100000
#define N_EDGES 800000
// IN=128, HID=256, OUT=128

// ---------------- count kernel ----------------
__global__ void count_k(const int* __restrict__ dst, float* __restrict__ cnt, int E) {
    int i = blockIdx.x * blockDim.x + threadIdx.x;
    if (i < E) atomicAdd(&cnt[dst[i]], 1.0f);
}

// ---------------- scatter kernel: 128-ch feature, float4 groups ----------------
__global__ void scatter128_k(const int* __restrict__ src, const int* __restrict__ dst,
                             const float* __restrict__ feat, float* __restrict__ acc, int E) {
    long long idx = (long long)blockIdx.x * blockDim.x + threadIdx.x;
    long long total = (long long)E * 32;
    if (idx >= total) return;
    int e = (int)(idx >> 5);
    int g = (int)(idx & 31);
    int s = src[e], d = dst[e];
    float4 v = ((const float4*)feat)[(long long)s * 32 + g];
    float* p = acc + ((long long)d * 32 + g) * 4;
    atomicAdd(p + 0, v.x);
    atomicAdd(p + 1, v.y);
    atomicAdd(p + 2, v.z);
    atomicAdd(p + 3, v.w);
}

// ================= tiled GEMM layer kernels =================
// Both layers are C[N x 256] = A'[N x 256] @ B'[256 x 256]^T with different
// A'/B' assembly and epilogue. Tile BM=BN=64, BK=64, 256 threads.
// Thread (tm=tid>>4, tn=tid&15) owns rows {tm+16i} x cols {tn+16j}, i,j in 0..3
// (both strided maps are bijections onto [0,64)).
// LDS rows padded to 68 floats (272B): 16B-aligned float4 access.

// ---- layer 1: h = relu([mean|x] @ [W1l|W1r]^T + b1l) ----
__global__ __launch_bounds__(256) void gemm1_k(
        const float* __restrict__ x, const float* __restrict__ agg1, const float* __restrict__ cnt,
        const float* __restrict__ W1l, const float* __restrict__ b1l, const float* __restrict__ W1r,
        float* __restrict__ h, int N) {
    __shared__ float As[64][68];
    __shared__ float Bs[64][68];
    const int m0 = blockIdx.x * 64;
    const int n0 = blockIdx.y * 64;
    const int tid = threadIdx.x;
    const int tm = tid >> 4, tn = tid & 15;

    float acc[4][4];
#pragma unroll
    for (int i = 0; i < 4; i++)
#pragma unroll
        for (int j = 0; j < 4; j++) acc[i][j] = 0.0f;

    for (int kt = 0; kt < 4; ++kt) {
        // ---- stage A-tile: kt<2 -> mean (agg1*rc), kt>=2 -> x ----
        const float* Asrc = (kt < 2) ? agg1 : x;
        const bool isMean = (kt < 2);
        const int af4 = (kt & 1) * 16;        // float4 offset within 128-float row
#pragma unroll
        for (int it = 0; it < 4; ++it) {
            int idx = tid + it * 256;
            int r = idx >> 4, kg = idx & 15;
            int gn = m0 + r;
            float4 v = make_float4(0, 0, 0, 0);
            if (gn < N) {
                v = ((const float4*)Asrc)[(long long)gn * 32 + af4 + kg];
                if (isMean) {
                    float rc = 1.0f / fmaxf(cnt[gn], 1.0f);
                    v.x *= rc; v.y *= rc; v.z *= rc; v.w *= rc;
                }
            }
            *(float4*)&As[r][kg * 4] = v;
        }
        // ---- stage B-tile: rows n0..n0+63 of B' (kt<2 -> W1l, else W1r) ----
        const float* Bsrc = (kt < 2) ? W1l : W1r;
#pragma unroll
        for (int it = 0; it < 4; ++it) {
            int idx = tid + it * 256;
            int r = idx >> 4, kg = idx & 15;
            float4 v = ((const float4*)Bsrc)[(n0 + r) * 32 + af4 + kg];
            *(float4*)&Bs[r][kg * 4] = v;
        }
        __syncthreads();
        // ---- compute ----
        for (int k = 0; k < 64; k += 4) {
            float4 a[4], b[4];
#pragma unroll
            for (int i = 0; i < 4; i++) a[i] = *(const float4*)&As[tm + 16 * i][k];
#pragma unroll
            for (int j = 0; j < 4; j++) b[j] = *(const float4*)&Bs[tn + 16 * j][k];
#pragma unroll
            for (int i = 0; i < 4; i++)
#pragma unroll
                for (int j = 0; j < 4; j++)
                    acc[i][j] += a[i].x * b[j].x + a[i].y * b[j].y
                               + a[i].z * b[j].z + a[i].w * b[j].w;
        }
        __syncthreads();
    }
    // ---- epilogue: bias + relu ----
#pragma unroll
    for (int i = 0; i < 4; i++) {
        int gn = m0 + tm + 16 * i;
        if (gn >= N) continue;
#pragma unroll
        for (int j = 0; j < 4; j++) {
            int c = n0 + tn + 16 * j;
            h[(long long)gn * 256 + c] = fmaxf(acc[i][j] + b1l[c], 0.0f);
        }
    }
}

// ---- layer 2: [g|r2] = h @ [W2l;W2r]^T  (no bias here) ----
__global__ __launch_bounds__(256) void gemm2_k(
        const float* __restrict__ h,
        const float* __restrict__ W2l, const float* __restrict__ W2r,
        float* __restrict__ g, float* __restrict__ r2, int N) {
    __shared__ float As[64][68];
    __shared__ float Bs[64][68];
    const int m0 = blockIdx.x * 64;
    const int nt = blockIdx.y;            // 0,1 -> g (W2l); 2,3 -> r2 (W2r)
    const int n0 = nt * 64;
    const int tid = threadIdx.x;
    const int tm = tid >> 4, tn = tid & 15;

    const float* Bsrc = (nt < 2) ? W2l : W2r;
    const int ro = (nt < 2) ? n0 : (n0 - 128);
    float* dstp = (nt < 2) ? g : r2;
    const int cb = ro;

    float acc[4][4];
#pragma unroll
    for (int i = 0; i < 4; i++)
#pragma unroll
        for (int j = 0; j < 4; j++) acc[i][j] = 0.0f;

    for (int kt = 0; kt < 4; ++kt) {
        const int kf4 = kt * 16;          // float4 offset within 256-float row
#pragma unroll
        for (int it = 0; it < 4; ++it) {
            int idx = tid + it * 256;
            int r = idx >> 4, kg = idx & 15;
            int gn = m0 + r;
            float4 v = make_float4(0, 0, 0, 0);
            if (gn < N) v = ((const float4*)h)[(long long)gn * 64 + kf4 + kg];
            *(float4*)&As[r][kg * 4] = v;
        }
#pragma unroll
        for (int it = 0; it < 4; ++it) {
            int idx = tid + it * 256;
            int r = idx >> 4, kg = idx & 15;
            float4 v = ((const float4*)Bsrc)[(ro + r) * 64 + kf4 + kg];
            *(float4*)&Bs[r][kg * 4] = v;
        }
        __syncthreads();
        for (int k = 0; k < 64; k += 4) {
            float4 a[4], b[4];
#pragma unroll
            for (int i = 0; i < 4; i++) a[i] = *(const float4*)&As[tm + 16 * i][k];
#pragma unroll
            for (int j = 0; j < 4; j++) b[j] = *(const float4*)&Bs[tn + 16 * j][k];
#pragma unroll
            for (int i = 0; i < 4; i++)
#pragma unroll
                for (int j = 0; j < 4; j++)
                    acc[i][j] += a[i].x * b[j].x + a[i].y * b[j].y
                               + a[i].z * b[j].z + a[i].w * b[j].w;
        }
        __syncthreads();
    }
#pragma unroll
    for (int i = 0; i < 4; i++) {
        int gn = m0 + tm + 16 * i;
        if (gn >= N) continue;
#pragma unroll
        for (int j = 0; j < 4; j++) {
            int c = cb + tn + 16 * j;     // 0..127 within dstp
            dstp[(long long)gn * 128 + c] = acc[i][j];
        }
    }
}

// ---------------- final: out = out/max(cnt,1) + b2l + r2 ----------------
__global__ void final_k(float* __restrict__ out, const float* __restrict__ r2,
                        const float* __restrict__ cnt, const float* __restrict__ b2l, int N) {
    long long i = (long long)blockIdx.x * blockDim.x + threadIdx.x;
    if (i >= (long long)N * 32) return;
    int n = (int)(i >> 5);
    int g = (int)(i & 31);
    float c = fmaxf(cnt[n], 1.0f);
    float rc = 1.0f / c;
    float4 a = ((float4*)out)[i];
    float4 r = ((const float4*)r2)[i];
    float4 b = ((const float4*)b2l)[g];
    float4 o;
    o.x = a.x * rc + r.x + b.x;
    o.y = a.y * rc + r.y + b.y;
    o.z = a.z * rc + r.z + b.z;
    o.w = a.w * rc + r.w + b.w;
    ((float4*)out)[i] = o;
}

extern "C" void kernel_launch(void* const* d_in, const int* in_sizes, int n_in,
                              void* d_out, int out_size, void* d_ws, size_t ws_size,
                              hipStream_t stream) {
    const float* x   = (const float*)d_in[0];
    const int*   ei  = (const int*)d_in[1];     // [2, E]: src = ei[0..E), dst = ei[E..2E)
    const float* W1l = (const float*)d_in[2];
    const float* b1l = (const float*)d_in[3];
    const float* W1r = (const float*)d_in[4];
    const float* W2l = (const float*)d_in[5];
    const float* b2l = (const float*)d_in[6];
    const float* W2r = (const float*)d_in[7];
    float* out = (float*)d_out;

    const int N = N_NODES, E = N_EDGES;
    const int* srcI = ei;
    const int* dstI = ei + E;

    char* ws = (char*)d_ws;
    size_t off = 0;
    auto alloc = [&](size_t bytes) {
        size_t o = off;
        off += (bytes + 511) & ~(size_t)511;
        return o;
    };
    size_t off_cnt  = alloc((size_t)N * 4);            // [N]
    size_t off_agg1 = alloc((size_t)N * 128 * 4);      // [N,128] — reused as g after gemm1
    size_t off_h    = alloc((size_t)N * 256 * 4);      // [N,256]
    size_t off_r2   = alloc((size_t)N * 128 * 4);      // [N,128]
    float* cnt  = (float*)(ws + off_cnt);
    float* agg1 = (float*)(ws + off_agg1);
    float* g    = (float*)(ws + off_agg1);             // reuse agg1 region
    float* h    = (float*)(ws + off_h);
    float* r2   = (float*)(ws + off_r2);

    (void)hipMemsetAsync(cnt, 0, (size_t)N * 4, stream);
    (void)hipMemsetAsync(agg1, 0, (size_t)N * 128 * 4, stream);
    (void)hipMemsetAsync(out, 0, (size_t)N * 128 * 4, stream);

    // counts
    count_k<<<(E + 255) / 256, 256, 0, stream>>>(dstI, cnt, E);

    // layer 1: scatter x -> agg1
    {
        long long total = (long long)E * 32;
        int blocks = (int)((total + 255) / 256);
        scatter128_k<<<blocks, 256, 0, stream>>>(srcI, dstI, x, agg1, E);
    }

    // gemm1: h = relu(mean1@W1l.T + b1l + x@W1r.T)
    {
        dim3 grid((N + 63) / 64, 4);
        gemm1_k<<<grid, 256, 0, stream>>>(x, agg1, cnt, W1l, b1l, W1r, h, N);
    }

    // gemm2: g = h@W2l.T, r2 = h@W2r.T
    {
        dim3 grid((N + 63) / 64, 4);
        gemm2_k<<<grid, 256, 0, stream>>>(h, W2l, W2r, g, r2, N);
    }

    // layer 2: scatter g -> out (segment sum)
    {
        long long total = (long long)E * 32;
        int blocks = (int)((total + 255) / 256);
        scatter128_k<<<blocks, 256, 0, stream>>>(srcI, dstI, g, out, E);
    }

    // final: out = out/max(cnt,1) + b2l + r2
    {
        long long total = (long long)N * 32;
        int blocks = (int)((total + 255) / 256);
        final_k<<<blocks, 256, 0, stream>>>(out, r2, cnt, b2l, N);
    }
}

// Round 5
// 744.451 us; speedup vs baseline: 11.3423x; 4.3561x over previous
//
#include <hip/hip_runtime.h>
#include <hip/hip_bf16.h>

#define N_NODES 100000
#define N_EDGES 800000
// IN=128, HID=256, OUT=128
// CSR scan geometry: 1024 elems/block
#define SCAN_CHUNK 1024
#define SCAN_NB ((N_NODES + SCAN_CHUNK - 1) / SCAN_CHUNK)   // 98

// ---------------- degree count (int atomics) ----------------
__global__ void count_int_k(const int* __restrict__ dst, int* __restrict__ cnt, int E) {
    int i = blockIdx.x * blockDim.x + threadIdx.x;
    if (i < E) atomicAdd(&cnt[dst[i]], 1);
}

// ---------------- scan pass 1: per-block local exclusive scan + block sums ----------------
__global__ __launch_bounds__(256) void scan1_k(const int* __restrict__ cnt,
                                               int* __restrict__ offs,
                                               int* __restrict__ bsums, int N) {
    __shared__ int s[256];
    int t = threadIdx.x;
    int base = blockIdx.x * SCAN_CHUNK + t * 4;
    int v0 = (base + 0 < N) ? cnt[base + 0] : 0;
    int v1 = (base + 1 < N) ? cnt[base + 1] : 0;
    int v2 = (base + 2 < N) ? cnt[base + 2] : 0;
    int v3 = (base + 3 < N) ? cnt[base + 3] : 0;
    int tsum = v0 + v1 + v2 + v3;
    s[t] = tsum;
    __syncthreads();
    for (int off = 1; off < 256; off <<= 1) {
        int val = (t >= off) ? s[t - off] : 0;
        __syncthreads();
        s[t] += val;
        __syncthreads();
    }
    int excl = s[t] - tsum;
    if (base + 0 < N) offs[base + 0] = excl;
    if (base + 1 < N) offs[base + 1] = excl + v0;
    if (base + 2 < N) offs[base + 2] = excl + v0 + v1;
    if (base + 3 < N) offs[base + 3] = excl + v0 + v1 + v2;
    if (t == 255) bsums[blockIdx.x] = s[255];
}

// ---------------- scan pass 2: single-block exclusive scan of block sums ----------------
__global__ __launch_bounds__(256) void scan2_k(const int* __restrict__ bsums,
                                               int* __restrict__ boffs, int nb) {
    __shared__ int s[256];
    int t = threadIdx.x;
    int v = (t < nb) ? bsums[t] : 0;
    s[t] = v;
    __syncthreads();
    for (int off = 1; off < 256; off <<= 1) {
        int val = (t >= off) ? s[t - off] : 0;
        __syncthreads();
        s[t] += val;
        __syncthreads();
    }
    if (t < nb) boffs[t] = s[t] - v;
}

// ---------------- scan pass 3: add block offsets; init cursor; set offs[N] ----------------
__global__ void scan3_k(int* __restrict__ offs, int* __restrict__ cursor,
                        const int* __restrict__ boffs, int N, int E) {
    int i = blockIdx.x * blockDim.x + threadIdx.x;
    if (i < N) {
        int v = offs[i] + boffs[i >> 10];
        offs[i] = v;
        cursor[i] = v;
    }
    if (i == 0) offs[N] = E;
}

// ---------------- bucket fill: perm[slot] = src(e), grouped by dst ----------------
__global__ void fill_k(const int* __restrict__ src, const int* __restrict__ dst,
                       int* __restrict__ cursor, int* __restrict__ perm, int E) {
    int e = blockIdx.x * blockDim.x + threadIdx.x;
    if (e < E) {
        int d = dst[e];
        int slot = atomicAdd(&cursor[d], 1);
        perm[slot] = src[e];
    }
}

// ---------------- gather-mean aggregation: 128 threads/node, 1 ch/thread ----------------
__global__ __launch_bounds__(256) void aggmean_k(const float* __restrict__ feat,
                                                 const int* __restrict__ perm,
                                                 const int* __restrict__ offs,
                                                 float* __restrict__ outm, int N) {
    int tid = threadIdx.x;
    int node = blockIdx.x * 2 + (tid >> 7);
    int ch = tid & 127;
    if (node >= N) return;
    int beg = offs[node], end = offs[node + 1];
    float a0 = 0.0f, a1 = 0.0f;
    int i = beg;
    for (; i + 1 < end; i += 2) {
        int s0 = perm[i], s1 = perm[i + 1];
        a0 += feat[(long long)s0 * 128 + ch];
        a1 += feat[(long long)s1 * 128 + ch];
    }
    if (i < end) a0 += feat[(long long)perm[i] * 128 + ch];
    float deg = (float)(end - beg);
    outm[(long long)node * 128 + ch] = (a0 + a1) / fmaxf(deg, 1.0f);
}

// ---------------- layer-2 aggregation fused with epilogue: out = mean(g) + r2 + b2l ----------------
__global__ __launch_bounds__(256) void aggout_k(const float* __restrict__ g,
                                                const int* __restrict__ perm,
                                                const int* __restrict__ offs,
                                                const float* __restrict__ r2,
                                                const float* __restrict__ b2l,
                                                float* __restrict__ out, int N) {
    int tid = threadIdx.x;
    int node = blockIdx.x * 2 + (tid >> 7);
    int ch = tid & 127;
    if (node >= N) return;
    int beg = offs[node], end = offs[node + 1];
    float a0 = 0.0f, a1 = 0.0f;
    int i = beg;
    for (; i + 1 < end; i += 2) {
        int s0 = perm[i], s1 = perm[i + 1];
        a0 += g[(long long)s0 * 128 + ch];
        a1 += g[(long long)s1 * 128 + ch];
    }
    if (i < end) a0 += g[(long long)perm[i] * 128 + ch];
    float deg = (float)(end - beg);
    float mean = (a0 + a1) / fmaxf(deg, 1.0f);
    out[(long long)node * 128 + ch] = mean + r2[(long long)node * 128 + ch] + b2l[ch];
}

// ================= tiled GEMM layer kernels =================
// C[N x 256] = A'[N x 256] @ B'[256 x 256]^T. Tile BM=BN=64, BK=64, 256 thr.
// Thread (tm=tid>>4, tn=tid&15) owns rows {tm+16i} x cols {tn+16j} (bijections).

// ---- layer 1: h = relu([mean|x] @ [W1l|W1r]^T + b1l); agg1 already holds the mean ----
__global__ __launch_bounds__(256) void gemm1_k(
        const float* __restrict__ x, const float* __restrict__ agg1,
        const float* __restrict__ W1l, const float* __restrict__ b1l, const float* __restrict__ W1r,
        float* __restrict__ h, int N) {
    __shared__ float As[64][68];
    __shared__ float Bs[64][68];
    const int m0 = blockIdx.x * 64;
    const int n0 = blockIdx.y * 64;
    const int tid = threadIdx.x;
    const int tm = tid >> 4, tn = tid & 15;

    float acc[4][4];
#pragma unroll
    for (int i = 0; i < 4; i++)
#pragma unroll
        for (int j = 0; j < 4; j++) acc[i][j] = 0.0f;

    for (int kt = 0; kt < 4; ++kt) {
        const float* Asrc = (kt < 2) ? agg1 : x;
        const int af4 = (kt & 1) * 16;
#pragma unroll
        for (int it = 0; it < 4; ++it) {
            int idx = tid + it * 256;
            int r = idx >> 4, kg = idx & 15;
            int gn = m0 + r;
            float4 v = make_float4(0, 0, 0, 0);
            if (gn < N) v = ((const float4*)Asrc)[(long long)gn * 32 + af4 + kg];
            *(float4*)&As[r][kg * 4] = v;
        }
        const float* Bsrc = (kt < 2) ? W1l : W1r;
#pragma unroll
        for (int it = 0; it < 4; ++it) {
            int idx = tid + it * 256;
            int r = idx >> 4, kg = idx & 15;
            float4 v = ((const float4*)Bsrc)[(n0 + r) * 32 + af4 + kg];
            *(float4*)&Bs[r][kg * 4] = v;
        }
        __syncthreads();
        for (int k = 0; k < 64; k += 4) {
            float4 a[4], b[4];
#pragma unroll
            for (int i = 0; i < 4; i++) a[i] = *(const float4*)&As[tm + 16 * i][k];
#pragma unroll
            for (int j = 0; j < 4; j++) b[j] = *(const float4*)&Bs[tn + 16 * j][k];
#pragma unroll
            for (int i = 0; i < 4; i++)
#pragma unroll
                for (int j = 0; j < 4; j++)
                    acc[i][j] += a[i].x * b[j].x + a[i].y * b[j].y
                               + a[i].z * b[j].z + a[i].w * b[j].w;
        }
        __syncthreads();
    }
#pragma unroll
    for (int i = 0; i < 4; i++) {
        int gn = m0 + tm + 16 * i;
        if (gn >= N) continue;
#pragma unroll
        for (int j = 0; j < 4; j++) {
            int c = n0 + tn + 16 * j;
            h[(long long)gn * 256 + c] = fmaxf(acc[i][j] + b1l[c], 0.0f);
        }
    }
}

// ---- layer 2: [g|r2] = h @ [W2l;W2r]^T ----
__global__ __launch_bounds__(256) void gemm2_k(
        const float* __restrict__ h,
        const float* __restrict__ W2l, const float* __restrict__ W2r,
        float* __restrict__ g, float* __restrict__ r2, int N) {
    __shared__ float As[64][68];
    __shared__ float Bs[64][68];
    const int m0 = blockIdx.x * 64;
    const int nt = blockIdx.y;            // 0,1 -> g (W2l); 2,3 -> r2 (W2r)
    const int tid = threadIdx.x;
    const int tm = tid >> 4, tn = tid & 15;

    const float* Bsrc = (nt < 2) ? W2l : W2r;
    const int ro = (nt & 1) * 64;         // row base within the 128-row weight
    float* dstp = (nt < 2) ? g : r2;

    float acc[4][4];
#pragma unroll
    for (int i = 0; i < 4; i++)
#pragma unroll
        for (int j = 0; j < 4; j++) acc[i][j] = 0.0f;

    for (int kt = 0; kt < 4; ++kt) {
        const int kf4 = kt * 16;
#pragma unroll
        for (int it = 0; it < 4; ++it) {
            int idx = tid + it * 256;
            int r = idx >> 4, kg = idx & 15;
            int gn = m0 + r;
            float4 v = make_float4(0, 0, 0, 0);
            if (gn < N) v = ((const float4*)h)[(long long)gn * 64 + kf4 + kg];
            *(float4*)&As[r][kg * 4] = v;
        }
#pragma unroll
        for (int it = 0; it < 4; ++it) {
            int idx = tid + it * 256;
            int r = idx >> 4, kg = idx & 15;
            float4 v = ((const float4*)Bsrc)[(ro + r) * 64 + kf4 + kg];
            *(float4*)&Bs[r][kg * 4] = v;
        }
        __syncthreads();
        for (int k = 0; k < 64; k += 4) {
            float4 a[4], b[4];
#pragma unroll
            for (int i = 0; i < 4; i++) a[i] = *(const float4*)&As[tm + 16 * i][k];
#pragma unroll
            for (int j = 0; j < 4; j++) b[j] = *(const float4*)&Bs[tn + 16 * j][k];
#pragma unroll
            for (int i = 0; i < 4; i++)
#pragma unroll
                for (int j = 0; j < 4; j++)
                    acc[i][j] += a[i].x * b[j].x + a[i].y * b[j].y
                               + a[i].z * b[j].z + a[i].w * b[j].w;
        }
        __syncthreads();
    }
#pragma unroll
    for (int i = 0; i < 4; i++) {
        int gn = m0 + tm + 16 * i;
        if (gn >= N) continue;
#pragma unroll
        for (int j = 0; j < 4; j++) {
            int c = ro + tn + 16 * j;     // 0..127 within dstp
            dstp[(long long)gn * 128 + c] = acc[i][j];
        }
    }
}

extern "C" void kernel_launch(void* const* d_in, const int* in_sizes, int n_in,
                              void* d_out, int out_size, void* d_ws, size_t ws_size,
                              hipStream_t stream) {
    const float* x   = (const float*)d_in[0];
    const int*   ei  = (const int*)d_in[1];     // [2, E]: src = ei[0..E), dst = ei[E..2E)
    const float* W1l = (const float*)d_in[2];
    const float* b1l = (const float*)d_in[3];
    const float* W1r = (const float*)d_in[4];
    const float* W2l = (const float*)d_in[5];
    const float* b2l = (const float*)d_in[6];
    const float* W2r = (const float*)d_in[7];
    float* out = (float*)d_out;

    const int N = N_NODES, E = N_EDGES;
    const int* srcI = ei;
    const int* dstI = ei + E;

    char* ws = (char*)d_ws;
    size_t off = 0;
    auto alloc = [&](size_t bytes) {
        size_t o = off;
        off += (bytes + 511) & ~(size_t)511;
        return o;
    };
    size_t off_cnt   = alloc((size_t)N * 4);           // int degree
    size_t off_offs  = alloc((size_t)(N + 1) * 4);     // CSR offsets
    size_t off_cur   = alloc((size_t)N * 4);           // fill cursor
    size_t off_bsum  = alloc((size_t)SCAN_NB * 4);
    size_t off_boff  = alloc((size_t)SCAN_NB * 4);
    size_t off_perm  = alloc((size_t)E * 4);           // src ids grouped by dst
    size_t off_agg1  = alloc((size_t)N * 128 * 4);     // mean (layer1); reused as g
    size_t off_h     = alloc((size_t)N * 256 * 4);
    size_t off_r2    = alloc((size_t)N * 128 * 4);
    int*   cntI  = (int*)(ws + off_cnt);
    int*   offs  = (int*)(ws + off_offs);
    int*   cur   = (int*)(ws + off_cur);
    int*   bsum  = (int*)(ws + off_bsum);
    int*   boff  = (int*)(ws + off_boff);
    int*   perm  = (int*)(ws + off_perm);
    float* agg1  = (float*)(ws + off_agg1);
    float* g     = (float*)(ws + off_agg1);            // reuse (after gemm1 reads agg1)
    float* h     = (float*)(ws + off_h);
    float* r2    = (float*)(ws + off_r2);

    // ---- CSR build (every call; graph replays everything) ----
    (void)hipMemsetAsync(cntI, 0, (size_t)N * 4, stream);
    count_int_k<<<(E + 255) / 256, 256, 0, stream>>>(dstI, cntI, E);
    scan1_k<<<SCAN_NB, 256, 0, stream>>>(cntI, offs, bsum, N);
    scan2_k<<<1, 256, 0, stream>>>(bsum, boff, SCAN_NB);
    scan3_k<<<(N + 255) / 256, 256, 0, stream>>>(offs, cur, boff, N, E);
    fill_k<<<(E + 255) / 256, 256, 0, stream>>>(srcI, dstI, cur, perm, E);

    // ---- layer 1 ----
    aggmean_k<<<(N + 1) / 2, 256, 0, stream>>>(x, perm, offs, agg1, N);
    {
        dim3 grid((N + 63) / 64, 4);
        gemm1_k<<<grid, 256, 0, stream>>>(x, agg1, W1l, b1l, W1r, h, N);
    }

    // ---- layer 2 ----
    {
        dim3 grid((N + 63) / 64, 4);
        gemm2_k<<<grid, 256, 0, stream>>>(h, W2l, W2r, g, r2, N);
    }
    aggout_k<<<(N + 1) / 2, 256, 0, stream>>>(g, perm, offs, r2, b2l, out, N);
}

// Round 7
// 495.163 us; speedup vs baseline: 17.0526x; 1.5034x over previous
//
#include <hip/hip_runtime.h>
#include <hip/hip_bf16.h>

#define N_NODES 100000
#define N_EDGES 800000
// IN=128, HID=256, OUT=128
#define SCAN_CHUNK 1024
#define SCAN_NB ((N_NODES + SCAN_CHUNK - 1) / SCAN_CHUNK)   // 98

typedef __attribute__((ext_vector_type(8))) short bf16x8;
typedef __attribute__((ext_vector_type(4))) float f32x4;

// ---------------- degree count (int atomics) ----------------
__global__ void count_int_k(const int* __restrict__ dst, int* __restrict__ cnt, int E) {
    int i = blockIdx.x * blockDim.x + threadIdx.x;
    if (i < E) atomicAdd(&cnt[dst[i]], 1);
}

// ---------------- scan pass 1 ----------------
__global__ __launch_bounds__(256) void scan1_k(const int* __restrict__ cnt,
                                               int* __restrict__ offs,
                                               int* __restrict__ bsums, int N) {
    __shared__ int s[256];
    int t = threadIdx.x;
    int base = blockIdx.x * SCAN_CHUNK + t * 4;
    int v0 = (base + 0 < N) ? cnt[base + 0] : 0;
    int v1 = (base + 1 < N) ? cnt[base + 1] : 0;
    int v2 = (base + 2 < N) ? cnt[base + 2] : 0;
    int v3 = (base + 3 < N) ? cnt[base + 3] : 0;
    int tsum = v0 + v1 + v2 + v3;
    s[t] = tsum;
    __syncthreads();
    for (int off = 1; off < 256; off <<= 1) {
        int val = (t >= off) ? s[t - off] : 0;
        __syncthreads();
        s[t] += val;
        __syncthreads();
    }
    int excl = s[t] - tsum;
    if (base + 0 < N) offs[base + 0] = excl;
    if (base + 1 < N) offs[base + 1] = excl + v0;
    if (base + 2 < N) offs[base + 2] = excl + v0 + v1;
    if (base + 3 < N) offs[base + 3] = excl + v0 + v1 + v2;
    if (t == 255) bsums[blockIdx.x] = s[255];
}

// ---------------- scan pass 2 ----------------
__global__ __launch_bounds__(256) void scan2_k(const int* __restrict__ bsums,
                                               int* __restrict__ boffs, int nb) {
    __shared__ int s[256];
    int t = threadIdx.x;
    int v = (t < nb) ? bsums[t] : 0;
    s[t] = v;
    __syncthreads();
    for (int off = 1; off < 256; off <<= 1) {
        int val = (t >= off) ? s[t - off] : 0;
        __syncthreads();
        s[t] += val;
        __syncthreads();
    }
    if (t < nb) boffs[t] = s[t] - v;
}

// ---------------- scan pass 3 ----------------
__global__ void scan3_k(int* __restrict__ offs, int* __restrict__ cursor,
                        const int* __restrict__ boffs, int N, int E) {
    int i = blockIdx.x * blockDim.x + threadIdx.x;
    if (i < N) {
        int v = offs[i] + boffs[i >> 10];
        offs[i] = v;
        cursor[i] = v;
    }
    if (i == 0) offs[N] = E;
}

// ---------------- bucket fill ----------------
__global__ void fill_k(const int* __restrict__ src, const int* __restrict__ dst,
                       int* __restrict__ cursor, int* __restrict__ perm, int E) {
    int e = blockIdx.x * blockDim.x + threadIdx.x;
    if (e < E) {
        int d = dst[e];
        int slot = atomicAdd(&cursor[d], 1);
        perm[slot] = src[e];
    }
}

// ---------------- gather-mean aggregation: 128 threads/node ----------------
__global__ __launch_bounds__(256) void aggmean_k(const float* __restrict__ feat,
                                                 const int* __restrict__ perm,
                                                 const int* __restrict__ offs,
                                                 float* __restrict__ outm, int N) {
    int tid = threadIdx.x;
    int node = blockIdx.x * 2 + (tid >> 7);
    int ch = tid & 127;
    if (node >= N) return;
    int beg = offs[node], end = offs[node + 1];
    float a0 = 0.0f, a1 = 0.0f;
    int i = beg;
    for (; i + 1 < end; i += 2) {
        int s0 = perm[i], s1 = perm[i + 1];
        a0 += feat[(long long)s0 * 128 + ch];
        a1 += feat[(long long)s1 * 128 + ch];
    }
    if (i < end) a0 += feat[(long long)perm[i] * 128 + ch];
    float deg = (float)(end - beg);
    outm[(long long)node * 128 + ch] = (a0 + a1) / fmaxf(deg, 1.0f);
}

// ---------------- layer-2 agg fused epilogue: out = mean(g) + r2 + b2l ----------------
__global__ __launch_bounds__(256) void aggout_k(const float* __restrict__ g,
                                                const int* __restrict__ perm,
                                                const int* __restrict__ offs,
                                                const float* __restrict__ r2,
                                                const float* __restrict__ b2l,
                                                float* __restrict__ out, int N) {
    int tid = threadIdx.x;
    int node = blockIdx.x * 2 + (tid >> 7);
    int ch = tid & 127;
    if (node >= N) return;
    int beg = offs[node], end = offs[node + 1];
    float a0 = 0.0f, a1 = 0.0f;
    int i = beg;
    for (; i + 1 < end; i += 2) {
        int s0 = perm[i], s1 = perm[i + 1];
        a0 += g[(long long)s0 * 128 + ch];
        a1 += g[(long long)s1 * 128 + ch];
    }
    if (i < end) a0 += g[(long long)perm[i] * 128 + ch];
    float deg = (float)(end - beg);
    float mean = (a0 + a1) / fmaxf(deg, 1.0f);
    out[(long long)node * 128 + ch] = mean + r2[(long long)node * 128 + ch] + b2l[ch];
}

// ================= split-bf16 MFMA GEMM =================
// C[N x 256] = A'[N x 256] @ B'[256 x 256]^T via bf16 MFMA, 2-term split:
// C ~= Ahi.Bhi + Ahi.Blo + Alo.Bhi  (residual ~2^-18 relative).
// Tile 128x128, 4 waves (2x2), each 64x64 = 4x4 mfma_f32_16x16x32_bf16 frags.
// K=256 in 4 tiles of BK=64. LDS = 4 x [128][64] bf16 = 64 KiB, XOR-swizzled
// (chunk ^= row&7) so frag ds_read_b128 is ~2-way conflict (free).
// LAYER==1: A'=[mean|x] (stride 128), B'=[W1l|W1r] k-split, bias+relu -> h.
// LAYER==2: A'=h (stride 256), weight chosen by n-tile, out split g|r2.

__device__ inline short2 cvt_split(float a) {
    unsigned u = __builtin_bit_cast(unsigned, a);
    unsigned r = u + 0x7FFF + ((u >> 16) & 1);
    unsigned short h = (unsigned short)(r >> 16);
    float hf = __builtin_bit_cast(float, (unsigned)h << 16);
    float l = a - hf;
    unsigned ul = __builtin_bit_cast(unsigned, l);
    unsigned rl = ul + 0x7FFF + ((ul >> 16) & 1);
    return make_short2((short)h, (short)(rl >> 16));
}

template <int LAYER>
__global__ __launch_bounds__(256, 2) void gemm_mfma_k(
        const float* __restrict__ Aa, const float* __restrict__ Ab,
        const float* __restrict__ B0, const float* __restrict__ B1,
        const float* __restrict__ bias,
        float* __restrict__ O0, float* __restrict__ O1, int N) {
    constexpr int AS = (LAYER == 1) ? 128 : 256;   // A row stride (floats)
    __shared__ short AsHi[128 * 64];
    __shared__ short AsLo[128 * 64];
    __shared__ short BsHi[128 * 64];
    __shared__ short BsLo[128 * 64];

    const int m0 = blockIdx.x * 128;
    const int n0 = blockIdx.y * 128;
    const int tid = threadIdx.x;
    const int lane = tid & 63;
    const int wid = tid >> 6;
    const int wm = wid >> 1, wn = wid & 1;
    const int lr = lane & 15, lg = lane >> 4;

    // B row sources for this block
    const float* Ba;
    const float* Bb;
    int BS;
    if constexpr (LAYER == 1) {
        Ba = B0 + (long long)n0 * 128;   // W1l rows n0..n0+127
        Bb = B1 + (long long)n0 * 128;   // W1r rows n0..n0+127
        BS = 128;
    } else {
        const float* Ws = (n0 == 0) ? B0 : B1;
        Ba = Ws;
        Bb = Ws + 128;
        BS = 256;
    }

    f32x4 acc[4][4];
#pragma unroll
    for (int i = 0; i < 4; i++)
#pragma unroll
        for (int j = 0; j < 4; j++) acc[i][j] = (f32x4)0.0f;

#pragma unroll
    for (int kt = 0; kt < 4; ++kt) {
        const float* Asrc = (kt < 2) ? Aa : Ab;
        const float* Bsrc = (kt < 2) ? Ba : Bb;
        const int koff = (kt & 1) * 64;

        __syncthreads();   // prev-tile readers done before overwrite
        // ---- stage: 1024 chunks of 8 elems each for A and B ----
#pragma unroll
        for (int it = 0; it < 4; ++it) {
            int cid = it * 256 + tid;          // 0..1023
            int row = cid >> 3, k8 = cid & 7;  // row 0..127, k-chunk 0..7
            int sc = k8 ^ (row & 7);
            // A
            {
                int gn = m0 + row;
                float4 v0 = make_float4(0, 0, 0, 0), v1 = make_float4(0, 0, 0, 0);
                if (gn < N) {
                    const float4* p = (const float4*)&Asrc[(long long)gn * AS + koff + k8 * 8];
                    v0 = p[0]; v1 = p[1];
                }
                bf16x8 hv, lv;
                short2 c0 = cvt_split(v0.x); hv[0] = c0.x; lv[0] = c0.y;
                short2 c1 = cvt_split(v0.y); hv[1] = c1.x; lv[1] = c1.y;
                short2 c2 = cvt_split(v0.z); hv[2] = c2.x; lv[2] = c2.y;
                short2 c3 = cvt_split(v0.w); hv[3] = c3.x; lv[3] = c3.y;
                short2 c4 = cvt_split(v1.x); hv[4] = c4.x; lv[4] = c4.y;
                short2 c5 = cvt_split(v1.y); hv[5] = c5.x; lv[5] = c5.y;
                short2 c6 = cvt_split(v1.z); hv[6] = c6.x; lv[6] = c6.y;
                short2 c7 = cvt_split(v1.w); hv[7] = c7.x; lv[7] = c7.y;
                *(bf16x8*)&AsHi[row * 64 + sc * 8] = hv;
                *(bf16x8*)&AsLo[row * 64 + sc * 8] = lv;
            }
            // B (rows always valid)
            {
                const float4* p = (const float4*)&Bsrc[(long long)row * BS + koff + k8 * 8];
                float4 v0 = p[0], v1 = p[1];
                bf16x8 hv, lv;
                short2 c0 = cvt_split(v0.x); hv[0] = c0.x; lv[0] = c0.y;
                short2 c1 = cvt_split(v0.y); hv[1] = c1.x; lv[1] = c1.y;
                short2 c2 = cvt_split(v0.z); hv[2] = c2.x; lv[2] = c2.y;
                short2 c3 = cvt_split(v0.w); hv[3] = c3.x; lv[3] = c3.y;
                short2 c4 = cvt_split(v1.x); hv[4] = c4.x; lv[4] = c4.y;
                short2 c5 = cvt_split(v1.y); hv[5] = c5.x; lv[5] = c5.y;
                short2 c6 = cvt_split(v1.z); hv[6] = c6.x; lv[6] = c6.y;
                short2 c7 = cvt_split(v1.w); hv[7] = c7.x; lv[7] = c7.y;
                *(bf16x8*)&BsHi[row * 64 + sc * 8] = hv;
                *(bf16x8*)&BsLo[row * 64 + sc * 8] = lv;
            }
        }
        __syncthreads();

        // ---- compute: 2 k-steps of 32 ----
#pragma unroll
        for (int ks = 0; ks < 2; ++ks) {
            bf16x8 bh[4], bl[4];
#pragma unroll
            for (int fc = 0; fc < 4; ++fc) {
                int c = wn * 64 + fc * 16 + lr;
                int ch = ks * 4 + lg;
                int sc = ch ^ (c & 7);
                bh[fc] = *(const bf16x8*)&BsHi[c * 64 + sc * 8];
                bl[fc] = *(const bf16x8*)&BsLo[c * 64 + sc * 8];
            }
#pragma unroll
            for (int fr = 0; fr < 4; ++fr) {
                int r = wm * 64 + fr * 16 + lr;
                int ch = ks * 4 + lg;
                int sc = ch ^ (r & 7);
                bf16x8 ah = *(const bf16x8*)&AsHi[r * 64 + sc * 8];
                bf16x8 al = *(const bf16x8*)&AsLo[r * 64 + sc * 8];
#pragma unroll
                for (int fc = 0; fc < 4; ++fc) {
                    acc[fr][fc] = __builtin_amdgcn_mfma_f32_16x16x32_bf16(al, bh[fc], acc[fr][fc], 0, 0, 0);
                    acc[fr][fc] = __builtin_amdgcn_mfma_f32_16x16x32_bf16(ah, bl[fc], acc[fr][fc], 0, 0, 0);
                    acc[fr][fc] = __builtin_amdgcn_mfma_f32_16x16x32_bf16(ah, bh[fc], acc[fr][fc], 0, 0, 0);
                }
            }
        }
    }

    // ---- epilogue: C/D map col=lane&15, row=(lane>>4)*4+reg ----
    if constexpr (LAYER == 1) {
#pragma unroll
        for (int fc = 0; fc < 4; ++fc) {
            int col = n0 + wn * 64 + fc * 16 + lr;
            float bv = bias[col];
#pragma unroll
            for (int fr = 0; fr < 4; ++fr) {
#pragma unroll
                for (int j = 0; j < 4; ++j) {
                    int row = m0 + wm * 64 + fr * 16 + lg * 4 + j;
                    if (row < N)
                        O0[(long long)row * 256 + col] = fmaxf(acc[fr][fc][j] + bv, 0.0f);
                }
            }
        }
    } else {
        float* dp = (n0 == 0) ? O0 : O1;
#pragma unroll
        for (int fc = 0; fc < 4; ++fc) {
            int col = wn * 64 + fc * 16 + lr;   // 0..127 within dp
#pragma unroll
            for (int fr = 0; fr < 4; ++fr) {
#pragma unroll
                for (int j = 0; j < 4; ++j) {
                    int row = m0 + wm * 64 + fr * 16 + lg * 4 + j;
                    if (row < N)
                        dp[(long long)row * 128 + col] = acc[fr][fc][j];
                }
            }
        }
    }
}

extern "C" void kernel_launch(void* const* d_in, const int* in_sizes, int n_in,
                              void* d_out, int out_size, void* d_ws, size_t ws_size,
                              hipStream_t stream) {
    const float* x   = (const float*)d_in[0];
    const int*   ei  = (const int*)d_in[1];     // [2, E]
    const float* W1l = (const float*)d_in[2];
    const float* b1l = (const float*)d_in[3];
    const float* W1r = (const float*)d_in[4];
    const float* W2l = (const float*)d_in[5];
    const float* b2l = (const float*)d_in[6];
    const float* W2r = (const float*)d_in[7];
    float* out = (float*)d_out;

    const int N = N_NODES, E = N_EDGES;
    const int* srcI = ei;
    const int* dstI = ei + E;

    char* ws = (char*)d_ws;
    size_t off = 0;
    auto alloc = [&](size_t bytes) {
        size_t o = off;
        off += (bytes + 511) & ~(size_t)511;
        return o;
    };
    size_t off_cnt   = alloc((size_t)N * 4);
    size_t off_offs  = alloc((size_t)(N + 1) * 4);
    size_t off_cur   = alloc((size_t)N * 4);
    size_t off_bsum  = alloc((size_t)SCAN_NB * 4);
    size_t off_boff  = alloc((size_t)SCAN_NB * 4);
    size_t off_perm  = alloc((size_t)E * 4);
    size_t off_agg1  = alloc((size_t)N * 128 * 4);     // mean; reused as g
    size_t off_h     = alloc((size_t)N * 256 * 4);
    size_t off_r2    = alloc((size_t)N * 128 * 4);
    int*   cntI  = (int*)(ws + off_cnt);
    int*   offs  = (int*)(ws + off_offs);
    int*   cur   = (int*)(ws + off_cur);
    int*   bsum  = (int*)(ws + off_bsum);
    int*   boff  = (int*)(ws + off_boff);
    int*   perm  = (int*)(ws + off_perm);
    float* agg1  = (float*)(ws + off_agg1);
    float* g     = (float*)(ws + off_agg1);
    float* h     = (float*)(ws + off_h);
    float* r2    = (float*)(ws + off_r2);

    // ---- CSR build ----
    (void)hipMemsetAsync(cntI, 0, (size_t)N * 4, stream);
    count_int_k<<<(E + 255) / 256, 256, 0, stream>>>(dstI, cntI, E);
    scan1_k<<<SCAN_NB, 256, 0, stream>>>(cntI, offs, bsum, N);
    scan2_k<<<1, 256, 0, stream>>>(bsum, boff, SCAN_NB);
    scan3_k<<<(N + 255) / 256, 256, 0, stream>>>(offs, cur, boff, N, E);
    fill_k<<<(E + 255) / 256, 256, 0, stream>>>(srcI, dstI, cur, perm, E);

    // ---- layer 1 ----
    aggmean_k<<<(N + 1) / 2, 256, 0, stream>>>(x, perm, offs, agg1, N);
    {
        dim3 grid((N + 127) / 128, 2);
        gemm_mfma_k<1><<<grid, 256, 0, stream>>>(agg1, x, W1l, W1r, b1l, h, nullptr, N);
    }

    // ---- layer 2 ----
    {
        dim3 grid((N + 127) / 128, 2);
        gemm_mfma_k<2><<<grid, 256, 0, stream>>>(h, h + 128, W2l, W2r, nullptr, g, r2, N);
    }
    aggout_k<<<(N + 1) / 2, 256, 0, stream>>>(g, perm, offs, r2, b2l, out, N);
}

// Round 8
// 488.043 us; speedup vs baseline: 17.3014x; 1.0146x over previous
//
#include <hip/hip_runtime.h>

#define N_NODES 100000
#define N_EDGES 800000
// IN=128, HID=256, OUT=128
#define SCAN_CHUNK 1024
#define SCAN_NB ((N_NODES + SCAN_CHUNK - 1) / SCAN_CHUNK)   // 98

typedef __attribute__((ext_vector_type(8))) short bf16x8;
typedef __attribute__((ext_vector_type(4))) float f32x4;

// ---------------- degree count (int atomics) ----------------
__global__ void count_int_k(const int* __restrict__ dst, int* __restrict__ cnt, int E) {
    int i = blockIdx.x * blockDim.x + threadIdx.x;
    if (i < E) atomicAdd(&cnt[dst[i]], 1);
}

// ---------------- scan pass 1 ----------------
__global__ __launch_bounds__(256) void scan1_k(const int* __restrict__ cnt,
                                               int* __restrict__ offs,
                                               int* __restrict__ bsums, int N) {
    __shared__ int s[256];
    int t = threadIdx.x;
    int base = blockIdx.x * SCAN_CHUNK + t * 4;
    int v0 = (base + 0 < N) ? cnt[base + 0] : 0;
    int v1 = (base + 1 < N) ? cnt[base + 1] : 0;
    int v2 = (base + 2 < N) ? cnt[base + 2] : 0;
    int v3 = (base + 3 < N) ? cnt[base + 3] : 0;
    int tsum = v0 + v1 + v2 + v3;
    s[t] = tsum;
    __syncthreads();
    for (int off = 1; off < 256; off <<= 1) {
        int val = (t >= off) ? s[t - off] : 0;
        __syncthreads();
        s[t] += val;
        __syncthreads();
    }
    int excl = s[t] - tsum;
    if (base + 0 < N) offs[base + 0] = excl;
    if (base + 1 < N) offs[base + 1] = excl + v0;
    if (base + 2 < N) offs[base + 2] = excl + v0 + v1;
    if (base + 3 < N) offs[base + 3] = excl + v0 + v1 + v2;
    if (t == 255) bsums[blockIdx.x] = s[255];
}

// ---------------- scan pass 2 ----------------
__global__ __launch_bounds__(256) void scan2_k(const int* __restrict__ bsums,
                                               int* __restrict__ boffs, int nb) {
    __shared__ int s[256];
    int t = threadIdx.x;
    int v = (t < nb) ? bsums[t] : 0;
    s[t] = v;
    __syncthreads();
    for (int off = 1; off < 256; off <<= 1) {
        int val = (t >= off) ? s[t - off] : 0;
        __syncthreads();
        s[t] += val;
        __syncthreads();
    }
    if (t < nb) boffs[t] = s[t] - v;
}

// ---------------- scan pass 3 ----------------
__global__ void scan3_k(int* __restrict__ offs, int* __restrict__ cursor,
                        const int* __restrict__ boffs, int N, int E) {
    int i = blockIdx.x * blockDim.x + threadIdx.x;
    if (i < N) {
        int v = offs[i] + boffs[i >> 10];
        offs[i] = v;
        cursor[i] = v;
    }
    if (i == 0) offs[N] = E;
}

// ---------------- bucket fill ----------------
__global__ void fill_k(const int* __restrict__ src, const int* __restrict__ dst,
                       int* __restrict__ cursor, int* __restrict__ perm, int E) {
    int e = blockIdx.x * blockDim.x + threadIdx.x;
    if (e < E) {
        int d = dst[e];
        int slot = atomicAdd(&cursor[d], 1);
        perm[slot] = src[e];
    }
}

// ---------------- split fp32 -> (bf16 hi, bf16 lo) ----------------
__device__ inline short2 cvt_split(float a) {
    unsigned u = __builtin_bit_cast(unsigned, a);
    unsigned r = u + 0x7FFF + ((u >> 16) & 1);
    unsigned short h = (unsigned short)(r >> 16);
    float hf = __builtin_bit_cast(float, (unsigned)h << 16);
    float l = a - hf;
    unsigned ul = __builtin_bit_cast(unsigned, l);
    unsigned rl = ul + 0x7FFF + ((ul >> 16) & 1);
    return make_short2((short)h, (short)(rl >> 16));
}

// ---------------- bulk pair-conversion kernel (8 floats/thread) ----------------
__global__ __launch_bounds__(256) void cvt_pair_k(const float* __restrict__ in,
                                                  short* __restrict__ hi,
                                                  short* __restrict__ lo, int n8) {
    int i = blockIdx.x * blockDim.x + threadIdx.x;
    if (i >= n8) return;
    const float4* p = (const float4*)in + (long long)i * 2;
    float4 v0 = p[0], v1 = p[1];
    bf16x8 hv, lv;
    short2 c;
    c = cvt_split(v0.x); hv[0] = c.x; lv[0] = c.y;
    c = cvt_split(v0.y); hv[1] = c.x; lv[1] = c.y;
    c = cvt_split(v0.z); hv[2] = c.x; lv[2] = c.y;
    c = cvt_split(v0.w); hv[3] = c.x; lv[3] = c.y;
    c = cvt_split(v1.x); hv[4] = c.x; lv[4] = c.y;
    c = cvt_split(v1.y); hv[5] = c.x; lv[5] = c.y;
    c = cvt_split(v1.z); hv[6] = c.x; lv[6] = c.y;
    c = cvt_split(v1.w); hv[7] = c.x; lv[7] = c.y;
    *(bf16x8*)&hi[(long long)i * 8] = hv;
    *(bf16x8*)&lo[(long long)i * 8] = lv;
}

// ---------------- gather-mean aggregation -> bf16 hi/lo pair ----------------
__global__ __launch_bounds__(256) void aggmean_k(const float* __restrict__ feat,
                                                 const int* __restrict__ perm,
                                                 const int* __restrict__ offs,
                                                 short* __restrict__ mhi,
                                                 short* __restrict__ mlo, int N) {
    int tid = threadIdx.x;
    int node = blockIdx.x * 2 + (tid >> 7);
    int ch = tid & 127;
    if (node >= N) return;
    int beg = offs[node], end = offs[node + 1];
    float a0 = 0.0f, a1 = 0.0f;
    int i = beg;
    for (; i + 1 < end; i += 2) {
        int s0 = perm[i], s1 = perm[i + 1];
        a0 += feat[(long long)s0 * 128 + ch];
        a1 += feat[(long long)s1 * 128 + ch];
    }
    if (i < end) a0 += feat[(long long)perm[i] * 128 + ch];
    float deg = (float)(end - beg);
    float mean = (a0 + a1) / fmaxf(deg, 1.0f);
    short2 c = cvt_split(mean);
    mhi[(long long)node * 128 + ch] = c.x;
    mlo[(long long)node * 128 + ch] = c.y;
}

// ---------------- layer-2 agg fused epilogue: out = mean(g) + r2 + b2l ----------------
__global__ __launch_bounds__(256) void aggout_k(const float* __restrict__ g,
                                                const int* __restrict__ perm,
                                                const int* __restrict__ offs,
                                                const float* __restrict__ r2,
                                                const float* __restrict__ b2l,
                                                float* __restrict__ out, int N) {
    int tid = threadIdx.x;
    int node = blockIdx.x * 2 + (tid >> 7);
    int ch = tid & 127;
    if (node >= N) return;
    int beg = offs[node], end = offs[node + 1];
    float a0 = 0.0f, a1 = 0.0f;
    int i = beg;
    for (; i + 1 < end; i += 2) {
        int s0 = perm[i], s1 = perm[i + 1];
        a0 += g[(long long)s0 * 128 + ch];
        a1 += g[(long long)s1 * 128 + ch];
    }
    if (i < end) a0 += g[(long long)perm[i] * 128 + ch];
    float deg = (float)(end - beg);
    float mean = (a0 + a1) / fmaxf(deg, 1.0f);
    out[(long long)node * 128 + ch] = mean + r2[(long long)node * 128 + ch] + b2l[ch];
}

// ---------------- async global->LDS, 16B/lane ----------------
__device__ inline void gload16(const void* g, void* l) {
    __builtin_amdgcn_global_load_lds(
        (const __attribute__((address_space(1))) unsigned int*)g,
        (__attribute__((address_space(3))) unsigned int*)l,
        16, 0, 0);
}

// ================= split-bf16 MFMA GEMM (pre-split operands) =================
// C ~= Ahi.Bhi + Ahi.Blo + Alo.Bhi. Tile 128x128, 4 waves (2x2), 4x4
// mfma_f32_16x16x32_bf16 frags each. Staging = global_load_lds with
// pre-swizzled per-lane source chunk (k8 = (lane&7)^(lane>>3)); LDS linear.
// Read side: chunk ch of row r lives at slot ch^(r&7).
template <int LAYER>
__global__ __launch_bounds__(256, 2) void gemm_mfma_k(
        const short* __restrict__ A0hi, const short* __restrict__ A0lo,
        const short* __restrict__ A1hi, const short* __restrict__ A1lo,
        const short* __restrict__ B0hi, const short* __restrict__ B0lo,
        const short* __restrict__ B1hi, const short* __restrict__ B1lo,
        const float* __restrict__ bias,
        float* __restrict__ O0, float* __restrict__ O1,
        short* __restrict__ OHi, short* __restrict__ OLo, int N) {
    constexpr int AS_ = (LAYER == 1) ? 128 : 256;   // A row stride
    constexpr int BS_ = (LAYER == 1) ? 128 : 256;   // B row stride
    __shared__ short AsHi[128 * 64];
    __shared__ short AsLo[128 * 64];
    __shared__ short BsHi[128 * 64];
    __shared__ short BsLo[128 * 64];

    const int m0 = blockIdx.x * 128;
    const int n0 = blockIdx.y * 128;
    const int tid = threadIdx.x;
    const int lane = tid & 63;
    const int wid = tid >> 6;
    const int wm = wid >> 1, wn = wid & 1;
    const int lr = lane & 15, lg = lane >> 4;

    // B half-sources (first/second K-half of B')
    const short *bh0, *bl0, *bh1, *bl1;
    if constexpr (LAYER == 1) {
        bh0 = B0hi + (long long)n0 * 128;   // W1l rows n0..
        bl0 = B0lo + (long long)n0 * 128;
        bh1 = B1hi + (long long)n0 * 128;   // W1r rows n0..
        bl1 = B1lo + (long long)n0 * 128;
    } else {
        const short* wh = (n0 == 0) ? B0hi : B1hi;
        const short* wl = (n0 == 0) ? B0lo : B1lo;
        bh0 = wh;       bl0 = wl;           // cols 0..127
        bh1 = wh + 128; bl1 = wl + 128;     // cols 128..255
    }

    // staging lane geometry
    const int r8 = lane >> 3;          // row within 8-row segment
    const int scs = lane & 7;          // LDS chunk slot this lane fills
    const int k8s = scs ^ r8;          // pre-swizzled global source chunk

    f32x4 acc[4][4];
#pragma unroll
    for (int i = 0; i < 4; i++)
#pragma unroll
        for (int j = 0; j < 4; j++) acc[i][j] = (f32x4)0.0f;

#pragma unroll
    for (int kt = 0; kt < 4; ++kt) {
        const short* Ahi = (kt < 2) ? A0hi : A1hi;
        const short* Alo = (kt < 2) ? A0lo : A1lo;
        const short* Bhi = (kt < 2) ? bh0 : bh1;
        const short* Blo = (kt < 2) ? bl0 : bl1;
        const int koff = (kt & 1) * 64;

        __syncthreads();   // prev-tile readers done before overwrite
#pragma unroll
        for (int it = 0; it < 4; ++it) {
            int seg = wid * 4 + it;            // 0..15 (8 rows each)
            int row = seg * 8 + r8;            // 0..127
            int gn = m0 + row;
            long long aoff = (long long)gn * AS_ + koff + k8s * 8;
            long long boff = (long long)row * BS_ + koff + k8s * 8;
            if (gn < N) {
                gload16(Ahi + aoff, &AsHi[seg * 512]);
                gload16(Alo + aoff, &AsLo[seg * 512]);
            }
            gload16(Bhi + boff, &BsHi[seg * 512]);
            gload16(Blo + boff, &BsLo[seg * 512]);
        }
        __syncthreads();   // drains vmcnt (global_load_lds) + barrier

        // ---- compute: 2 k-steps of 32 ----
#pragma unroll
        for (int ks = 0; ks < 2; ++ks) {
            bf16x8 bh[4], bl[4];
#pragma unroll
            for (int fc = 0; fc < 4; ++fc) {
                int c = wn * 64 + fc * 16 + lr;
                int ch = ks * 4 + lg;
                int sc = ch ^ (c & 7);
                bh[fc] = *(const bf16x8*)&BsHi[c * 64 + sc * 8];
                bl[fc] = *(const bf16x8*)&BsLo[c * 64 + sc * 8];
            }
#pragma unroll
            for (int fr = 0; fr < 4; ++fr) {
                int r = wm * 64 + fr * 16 + lr;
                int ch = ks * 4 + lg;
                int sc = ch ^ (r & 7);
                bf16x8 ah = *(const bf16x8*)&AsHi[r * 64 + sc * 8];
                bf16x8 al = *(const bf16x8*)&AsLo[r * 64 + sc * 8];
#pragma unroll
                for (int fc = 0; fc < 4; ++fc) {
                    acc[fr][fc] = __builtin_amdgcn_mfma_f32_16x16x32_bf16(al, bh[fc], acc[fr][fc], 0, 0, 0);
                    acc[fr][fc] = __builtin_amdgcn_mfma_f32_16x16x32_bf16(ah, bl[fc], acc[fr][fc], 0, 0, 0);
                    acc[fr][fc] = __builtin_amdgcn_mfma_f32_16x16x32_bf16(ah, bh[fc], acc[fr][fc], 0, 0, 0);
                }
            }
        }
    }

    // ---- epilogue: C/D map col=lane&15, row=(lane>>4)*4+reg ----
    if constexpr (LAYER == 1) {
#pragma unroll
        for (int fc = 0; fc < 4; ++fc) {
            int col = n0 + wn * 64 + fc * 16 + lr;
            float bv = bias[col];
#pragma unroll
            for (int fr = 0; fr < 4; ++fr) {
#pragma unroll
                for (int j = 0; j < 4; ++j) {
                    int row = m0 + wm * 64 + fr * 16 + lg * 4 + j;
                    if (row < N) {
                        float val = fmaxf(acc[fr][fc][j] + bv, 0.0f);
                        short2 cc = cvt_split(val);
                        OHi[(long long)row * 256 + col] = cc.x;
                        OLo[(long long)row * 256 + col] = cc.y;
                    }
                }
            }
        }
    } else {
        float* dp = (n0 == 0) ? O0 : O1;
#pragma unroll
        for (int fc = 0; fc < 4; ++fc) {
            int col = wn * 64 + fc * 16 + lr;   // 0..127 within dp
#pragma unroll
            for (int fr = 0; fr < 4; ++fr) {
#pragma unroll
                for (int j = 0; j < 4; ++j) {
                    int row = m0 + wm * 64 + fr * 16 + lg * 4 + j;
                    if (row < N)
                        dp[(long long)row * 128 + col] = acc[fr][fc][j];
                }
            }
        }
    }
}

extern "C" void kernel_launch(void* const* d_in, const int* in_sizes, int n_in,
                              void* d_out, int out_size, void* d_ws, size_t ws_size,
                              hipStream_t stream) {
    const float* x   = (const float*)d_in[0];
    const int*   ei  = (const int*)d_in[1];     // [2, E]
    const float* W1l = (const float*)d_in[2];
    const float* b1l = (const float*)d_in[3];
    const float* W1r = (const float*)d_in[4];
    const float* W2l = (const float*)d_in[5];
    const float* b2l = (const float*)d_in[6];
    const float* W2r = (const float*)d_in[7];
    float* out = (float*)d_out;

    const int N = N_NODES, E = N_EDGES;
    const int* srcI = ei;
    const int* dstI = ei + E;

    char* ws = (char*)d_ws;
    size_t off = 0;
    auto alloc = [&](size_t bytes) {
        size_t o = off;
        off += (bytes + 511) & ~(size_t)511;
        return o;
    };
    size_t off_cnt   = alloc((size_t)N * 4);
    size_t off_offs  = alloc((size_t)(N + 1) * 4);
    size_t off_cur   = alloc((size_t)N * 4);
    size_t off_bsum  = alloc((size_t)SCAN_NB * 4);
    size_t off_boff  = alloc((size_t)SCAN_NB * 4);
    size_t off_perm  = alloc((size_t)E * 4);
    size_t off_x2    = alloc((size_t)N * 128 * 4);     // xhi | xlo
    size_t off_m2    = alloc((size_t)N * 128 * 4);     // mhi | mlo; reused as g (fp32)
    size_t off_h2    = alloc((size_t)N * 256 * 4);     // hhi | hlo
    size_t off_r2    = alloc((size_t)N * 128 * 4);     // fp32
    size_t off_w     = alloc((size_t)8 * 256 * 128 * 2); // 4 weights x hi/lo
    int*   cntI  = (int*)(ws + off_cnt);
    int*   offs  = (int*)(ws + off_offs);
    int*   cur   = (int*)(ws + off_cur);
    int*   bsum  = (int*)(ws + off_bsum);
    int*   boff  = (int*)(ws + off_boff);
    int*   perm  = (int*)(ws + off_perm);
    short* xhi   = (short*)(ws + off_x2);
    short* xlo   = xhi + (size_t)N * 128;
    short* mhi   = (short*)(ws + off_m2);
    short* mlo   = mhi + (size_t)N * 128;
    float* g     = (float*)(ws + off_m2);              // aliases mean (dead after gemm1)
    short* hhi   = (short*)(ws + off_h2);
    short* hlo   = hhi + (size_t)N * 256;
    float* r2    = (float*)(ws + off_r2);
    short* wbuf  = (short*)(ws + off_w);
    const int WSZ = 256 * 128;
    short* w1lhi = wbuf;            short* w1llo = wbuf + WSZ;
    short* w1rhi = wbuf + 2 * WSZ;  short* w1rlo = wbuf + 3 * WSZ;
    short* w2lhi = wbuf + 4 * WSZ;  short* w2llo = wbuf + 5 * WSZ;
    short* w2rhi = wbuf + 6 * WSZ;  short* w2rlo = wbuf + 7 * WSZ;

    // ---- CSR build ----
    (void)hipMemsetAsync(cntI, 0, (size_t)N * 4, stream);
    count_int_k<<<(E + 255) / 256, 256, 0, stream>>>(dstI, cntI, E);
    scan1_k<<<SCAN_NB, 256, 0, stream>>>(cntI, offs, bsum, N);
    scan2_k<<<1, 256, 0, stream>>>(bsum, boff, SCAN_NB);
    scan3_k<<<(N + 255) / 256, 256, 0, stream>>>(offs, cur, boff, N, E);
    fill_k<<<(E + 255) / 256, 256, 0, stream>>>(srcI, dstI, cur, perm, E);

    // ---- pre-split conversions ----
    {
        int n8x = N * 16;                          // N*128/8
        cvt_pair_k<<<(n8x + 255) / 256, 256, 0, stream>>>(x, xhi, xlo, n8x);
        int n8w = WSZ / 8;                         // 4096
        cvt_pair_k<<<(n8w + 255) / 256, 256, 0, stream>>>(W1l, w1lhi, w1llo, n8w);
        cvt_pair_k<<<(n8w + 255) / 256, 256, 0, stream>>>(W1r, w1rhi, w1rlo, n8w);
        cvt_pair_k<<<(n8w + 255) / 256, 256, 0, stream>>>(W2l, w2lhi, w2llo, n8w);
        cvt_pair_k<<<(n8w + 255) / 256, 256, 0, stream>>>(W2r, w2rhi, w2rlo, n8w);
    }

    // ---- layer 1 ----
    aggmean_k<<<(N + 1) / 2, 256, 0, stream>>>(x, perm, offs, mhi, mlo, N);
    {
        dim3 grid((N + 127) / 128, 2);
        gemm_mfma_k<1><<<grid, 256, 0, stream>>>(mhi, mlo, xhi, xlo,
                                                 w1lhi, w1llo, w1rhi, w1rlo,
                                                 b1l, nullptr, nullptr, hhi, hlo, N);
    }

    // ---- layer 2 ----
    {
        dim3 grid((N + 127) / 128, 2);
        gemm_mfma_k<2><<<grid, 256, 0, stream>>>(hhi, hlo, hhi + 128, hlo + 128,
                                                 w2lhi, w2llo, w2rhi, w2rlo,
                                                 nullptr, g, r2, nullptr, nullptr, N);
    }
    aggout_k<<<(N + 1) / 2, 256, 0, stream>>>(g, perm, offs, r2, b2l, out, N);
}